// Round 7
// baseline (201.023 us; speedup 1.0000x reference)
//
#include <hip/hip_runtime.h>
#include <hip/hip_bf16.h>

#define TAPS 901
#define CB 256
#define R 15
#define NK 240                  // trimmed combined-kernel taps
#define OPB (CB * R)            // 3840 pixels per bin_dot block
#define WL 4864                 // prefix buffer length (W[0]=0 + 4863 values)
#define CHUNK 19                // 256*19 = 4864 (odd stride -> conflict-free)

// ---------------------------------------------------------------------------
// prep0 (1 block): build rot/gauss kernels, combined kernel comb=conv(rot,
// gauss) trimmed to NK taps. bounds = {clo4, flo, fhi}.
// ---------------------------------------------------------------------------
__global__ __launch_bounds__(1024) void prep0(
    const float* __restrict__ lns, const float* __restrict__ lnv,
    float* __restrict__ comb_w, int* __restrict__ bounds) {
  __shared__ float rk[1024], gk[1024], red[1024];
  __shared__ float ck[2048];
  __shared__ int sb[8];  // {rlo,rhi,glo,ghi,clo,chi}
  const int t = threadIdx.x;
  if (t < 8) sb[t] = (t & 1) ? -1 : 4096;
  __syncthreads();

  const float sigma = 0.01f + expf(lns[0]);
  const float vsini = 0.9f + expf(lnv[0]);

  float rv = 0.f, gv = 0.f;
  if (t < TAPS) {
    float g = -4.5f + 0.01f * (float)t;
    float x = (299792.458f * g / 10500.0f) / vsini;
    float x2 = fminf(x * x, 1.0f);
    if (x2 < 1.0f) rv = 2.0f * sqrtf(1.0f - x2);  // 0.99999999f rounds to 1.0f
    gv = (1.0f / (sigma * sqrtf(2.0f * 3.1415926654f))) *
         expf(-0.5f * g * g / (sigma * sigma)) * 0.01f;
  }
  red[t] = rv;
  __syncthreads();
  for (int s = 512; s > 0; s >>= 1) {
    if (t < s) red[t] += red[t + s];
    __syncthreads();
  }
  const float rsum = red[0];

  const float rw = (t < TAPS) ? rv / rsum : 0.f;
  rk[t] = rw;
  gk[t] = gv;
  if (t < TAPS) {
    if (rw != 0.f)          { atomicMin(&sb[0], t); atomicMax(&sb[1], t); }
    if (fabsf(gv) > 1e-10f) { atomicMin(&sb[2], t); atomicMax(&sb[3], t); }
  }
  __syncthreads();
  const int rlo = sb[0], rhi = sb[1], glo = sb[2], ghi = sb[3];

  for (int t2 = t; t2 < 2048; t2 += 1024) {
    float c = 0.f;
    if (t2 <= 1800) {
      int jmin = rlo > t2 - ghi ? rlo : t2 - ghi;
      int jmax = rhi < t2 - glo ? rhi : t2 - glo;
      for (int j = jmin; j <= jmax; ++j) c += rk[j] * gk[t2 - j];
    }
    ck[t2] = c;
    comb_w[t2] = c;
    if (t2 <= 1800 && fabsf(c) > 1e-12f) { atomicMin(&sb[4], t2); atomicMax(&sb[5], t2); }
  }
  __syncthreads();
  if (t == 0) {
    int clo = sb[4], chi = sb[5];
    if (chi < clo) { clo = 900; chi = 900; }
    while (chi - (clo & ~3) + 1 > NK) {
      if (fabsf(ck[clo]) <= fabsf(ck[chi])) ++clo; else --chi;
    }
    int flo = 450 - glo; if (flo < 0) flo = 0;
    int fhi = ghi - 450; if (fhi < 0) fhi = 0;
    bounds[0] = clo & ~3; bounds[1] = flo; bounds[2] = fhi;
  }
}

// ---------------------------------------------------------------------------
// prep1 (2 blocks): for edge pixels (i<flo, i>=n-fhi) add per-bin delta =
// exact_two_stage_c[i] - combined_trimmed_c[i] into edgeCorr (zeroed before).
// ---------------------------------------------------------------------------
__global__ __launch_bounds__(1024) void prep1(
    const float* __restrict__ lns, const float* __restrict__ lnv,
    const float* __restrict__ flux, const int* __restrict__ ids,
    const float* __restrict__ comb_w, const int* __restrict__ bounds,
    float* __restrict__ edgeCorr, int n) {
  __shared__ float rk[1024], gk[1024], red[1024], rbuf[928];
  __shared__ int sb[4];
  const int t = threadIdx.x;
  if (t < 4) sb[t] = (t & 1) ? -1 : 4096;
  __syncthreads();

  const float sigma = 0.01f + expf(lns[0]);
  const float vsini = 0.9f + expf(lnv[0]);
  float rv = 0.f, gv = 0.f;
  if (t < TAPS) {
    float g = -4.5f + 0.01f * (float)t;
    float x = (299792.458f * g / 10500.0f) / vsini;
    float x2 = fminf(x * x, 1.0f);
    if (x2 < 1.0f) rv = 2.0f * sqrtf(1.0f - x2);
    gv = (1.0f / (sigma * sqrtf(2.0f * 3.1415926654f))) *
         expf(-0.5f * g * g / (sigma * sigma)) * 0.01f;
  }
  red[t] = rv;
  __syncthreads();
  for (int s = 512; s > 0; s >>= 1) {
    if (t < s) red[t] += red[t + s];
    __syncthreads();
  }
  const float rsum = red[0];
  rk[t] = (t < TAPS) ? rv / rsum : 0.f;
  gk[t] = gv;
  if (t < TAPS) {
    if (rk[t] != 0.f)       { atomicMin(&sb[0], t); atomicMax(&sb[1], t); }
    if (fabsf(gv) > 1e-10f) { atomicMin(&sb[2], t); atomicMax(&sb[3], t); }
  }
  __syncthreads();
  const int rlo = sb[0], rhi = sb[1], glo = sb[2], ghi = sb[3];
  int flo = 450 - glo; if (flo < 0) flo = 0;
  int fhi = ghi - 450; if (fhi < 0) fhi = 0;
  const int m = flo + fhi;
  const int clo4 = bounds[0];

  if (blockIdx.x == 0) {
    for (int j = t; j < m; j += 1024) {
      float s = 0.f;
      int j0 = 450 - j > rlo ? 450 - j : rlo;
      for (int j2 = j0; j2 <= rhi; ++j2) s += rk[j2] * flux[j + j2 - 450];
      rbuf[j] = s;
    }
    __syncthreads();
    for (int i = t; i < flo; i += 1024) {
      float ex = 0.f;
      int k0 = 450 - i > glo ? 450 - i : glo;
      for (int k = k0; k <= ghi; ++k) ex += gk[k] * rbuf[i + k - 450];
      float cb = 0.f;
      for (int t2 = 0; t2 < NK; ++t2) {
        int q = i + clo4 + t2 - 900;
        if (q >= 0 && q < n) cb = fmaf(comb_w[clo4 + t2], flux[q], cb);
      }
      atomicAdd(&edgeCorr[ids[i]], ex - cb);
    }
  } else {
    const int jbase = n - m;
    for (int jj = t; jj < m; jj += 1024) {
      int j = jbase + jj;
      float s = 0.f;
      int j2hi = n - 1 + 450 - j < rhi ? n - 1 + 450 - j : rhi;
      for (int j2 = rlo; j2 <= j2hi; ++j2) s += rk[j2] * flux[j + j2 - 450];
      rbuf[jj] = s;
    }
    __syncthreads();
    for (int ii = t; ii < fhi; ii += 1024) {
      int i = n - fhi + ii;
      float ex = 0.f;
      int khi = n - 1 + 450 - i < ghi ? n - 1 + 450 - i : ghi;
      for (int k = glo; k <= khi; ++k) ex += gk[k] * rbuf[i + k - 450 - jbase];
      float cb = 0.f;
      for (int t2 = 0; t2 < NK; ++t2) {
        int q = i + clo4 + t2 - 900;
        if (q >= 0 && q < n) cb = fmaf(comb_w[clo4 + t2], flux[q], cb);
      }
      atomicAdd(&edgeCorr[ids[i]], ex - cb);
    }
  }
}

// ---------------------------------------------------------------------------
// build_bstart: bstart[b] = first pixel index with id >= b (sorted ids);
// bstart[nbins] = n. 8 pixels/thread, int4 loads.
// ---------------------------------------------------------------------------
__global__ __launch_bounds__(256) void build_bstart(
    const int* __restrict__ ids, int* __restrict__ bstart, int n, int nbins) {
  const int gid = blockIdx.x * 256 + threadIdx.x;
  const int p0 = gid * 8;
  if (p0 >= n) return;
  int prev = (p0 == 0) ? -1 : ids[p0 - 1];
  const int4 a = *reinterpret_cast<const int4*>(ids + p0);
  const int4 b4 = *reinterpret_cast<const int4*>(ids + p0 + 4);
  const int v[8] = {a.x, a.y, a.z, a.w, b4.x, b4.y, b4.z, b4.w};
#pragma unroll
  for (int r = 0; r < 8; ++r) {
    const int id = v[r];
    if (id != prev) {
      for (int b = prev + 1; b <= id; ++b) bstart[b] = p0 + r;
      prev = id;
    }
  }
  if (p0 + 8 >= n) {
    for (int b = prev + 1; b <= nbins; ++b) bstart[b] = n;
  }
}

// ---------------------------------------------------------------------------
// bin_dot: per-bin sums via the prefix trick.
//   binsum(b) = sum_t w[t]*(F[e-1+t-900] - F[s-1+t-900]), F = prefix(flux)
// Block owns pixels [blockBase, blockBase+OPB); handles bins STARTING there.
// Local prefix W (fp32, window magnitudes ~4.8k -> error ~2e-3 on sums ~12).
// W[0]=0, W[1+j] = inclusive scan of f_zeropad[wstart+j]. Then
//   binsum = sum_t' wl[t']*(W[e-blockBase+t'] - W[s-blockBase+t'])
// count = e-s; mean+clip written directly to out. No atomics.
// ---------------------------------------------------------------------------
__global__ __launch_bounds__(CB) void bin_dot(
    const float* __restrict__ flux, const float* __restrict__ comb_w,
    const int* __restrict__ bounds, const int* __restrict__ ids,
    const int* __restrict__ bstart, const float* __restrict__ edgeCorr,
    float* __restrict__ out, int n, int nbins) {
  __shared__ float W[WL];
  __shared__ float wl[NK];
  __shared__ float caux[CB];
  const int tid = threadIdx.x;
  const int clo4 = __builtin_amdgcn_readfirstlane(bounds[0]);
  const int blockBase = blockIdx.x * OPB;
  const int wstart = blockBase - 900 + clo4;

  if (tid == 0) W[0] = 0.f;
  for (int j = tid; j < WL - 1; j += CB) {
    const int g = wstart + j;
    W[1 + j] = ((unsigned)g < (unsigned)n) ? flux[g] : 0.f;
  }
  if (tid < NK) wl[tid] = comb_w[clo4 + tid];
  __syncthreads();

  // in-place inclusive scan of W[1..WL-1]: serial chunk scan + block scan
  {
    const int base = 1 + tid * CHUNK;
    const int lim = min(base + CHUNK, WL);
    float s = 0.f;
    for (int j = base; j < lim; ++j) { s += W[j]; W[j] = s; }
    caux[tid] = s;
    __syncthreads();
    for (int off = 1; off < CB; off <<= 1) {
      const float v = (tid >= off) ? caux[tid - off] : 0.f;
      __syncthreads();
      caux[tid] += v;
      __syncthreads();
    }
    const float offv = (tid == 0) ? 0.f : caux[tid - 1];
    for (int j = base; j < lim; ++j) W[j] += offv;
  }
  __syncthreads();

  // bin range owned by this block
  const int blo = (blockBase == 0) ? 0 : ids[blockBase - 1] + 1;
  const int lastpix = min(blockBase + OPB, n) - 1;
  int bhi = ids[lastpix];
  if (blockBase + OPB >= n) bhi = nbins - 1;  // cover trailing empty bins
  const int oe_last = bstart[bhi + 1] - blockBase;
  const bool fallback = (oe_last + NK > WL);  // block-uniform safety net

  for (int b = blo + tid; b <= bhi; b += CB) {
    const int s = bstart[b], e = bstart[b + 1];
    float a0 = 0.f, a1 = 0.f, a2 = 0.f, a3 = 0.f;
    if (!fallback) {
      const int os = s - blockBase, oe = e - blockBase;
#pragma unroll 4
      for (int t2 = 0; t2 < NK; t2 += 4) {
        a0 = fmaf(wl[t2 + 0], W[oe + t2 + 0] - W[os + t2 + 0], a0);
        a1 = fmaf(wl[t2 + 1], W[oe + t2 + 1] - W[os + t2 + 1], a1);
        a2 = fmaf(wl[t2 + 2], W[oe + t2 + 2] - W[os + t2 + 2], a2);
        a3 = fmaf(wl[t2 + 3], W[oe + t2 + 3] - W[os + t2 + 3], a3);
      }
    } else {
      for (int i = s; i < e; ++i)
        for (int t2 = 0; t2 < NK; ++t2) {
          const int q = i + clo4 + t2 - 900;
          if ((unsigned)q < (unsigned)n) a0 = fmaf(wl[t2], flux[q], a0);
        }
    }
    const float sum = ((a0 + a1) + (a2 + a3)) + edgeCorr[b];
    if (b >= 1 && b <= nbins - 2) {
      const int c = e - s;
      const float mean = sum / (float)(c > 1 ? c : 1);
      out[b - 1] = fminf(fmaxf(mean, 0.f), 1.f);
    }
  }
}

// ---------------------------------------------------------------------------
extern "C" void kernel_launch(void* const* d_in, const int* in_sizes, int n_in,
                              void* d_out, int out_size, void* d_ws,
                              size_t ws_size, hipStream_t stream) {
  const float* flux = (const float*)d_in[0];
  const float* lns  = (const float*)d_in[1];
  const float* lnv  = (const float*)d_in[2];
  const int*   ids  = (const int*)d_in[3];
  float* out = (float*)d_out;
  const int n = in_sizes[0];
  const int nbins = out_size + 2;

  // ws layout (floats): comb_w[2048] | bounds(int)[64] | edgeCorr[nbins] |
  //                     bstart(int)[nbins+1]
  float* ws       = (float*)d_ws;
  float* comb_w   = ws;
  int*   bounds   = (int*)(ws + 2048);
  float* edgeCorr = ws + 2112;
  int*   bstart   = (int*)(edgeCorr + nbins);

  hipMemsetAsync(edgeCorr, 0, (size_t)nbins * sizeof(float), stream);
  prep0<<<1, 1024, 0, stream>>>(lns, lnv, comb_w, bounds);
  prep1<<<2, 1024, 0, stream>>>(lns, lnv, flux, ids, comb_w, bounds,
                                edgeCorr, n);
  build_bstart<<<(n / 8 + 255) / 256, 256, 0, stream>>>(ids, bstart, n, nbins);
  const int nblk = (n + OPB - 1) / OPB;
  bin_dot<<<nblk, CB, 0, stream>>>(flux, comb_w, bounds, ids, bstart,
                                   edgeCorr, out, n, nbins);
}

// Round 8
// 138.625 us; speedup vs baseline: 1.4501x; 1.4501x over previous
//
#include <hip/hip_runtime.h>
#include <hip/hip_bf16.h>

#define TAPS 901
#define CB 256
#define R 11                    // outputs/thread; odd -> conflict-free ring
#define NGRP 22
#define NK (R * NGRP)           // 242 trimmed taps
#define OPB (CB * R)            // 2816 outputs per block
#define STAGE_N 3060            // staged floats: OPB + NK rounded to x4
#define TILE 3072
#define WPAD 12                 // padded weight slots per group (3 float4)

__device__ __forceinline__ float4 ld4(const float* p) {
  return *reinterpret_cast<const float4*>(p);
}

// ---------------------------------------------------------------------------
// Kernel 1 (3 blocks): block 0 builds comb = conv(rot,gauss) trimmed to NK
// taps + bounds{clo4, flo, fhi}; blocks 1/2 recompute rot/gauss locally and
// do the exact two-stage conv for the lo/hi edge pixels (i<flo, i>=n-fhi),
// scattered into sums (conv_scatter skips those pixels).
// ---------------------------------------------------------------------------
__global__ __launch_bounds__(1024) void prep(
    const float* __restrict__ lns, const float* __restrict__ lnv,
    const float* __restrict__ flux, const int* __restrict__ ids,
    float* __restrict__ comb_w, int* __restrict__ bounds,
    float* __restrict__ sums, int n) {
  __shared__ float rk[1024], gk[1024], red[1024];
  __shared__ float ck[2048];            // block0: comb; blocks1/2: rbuf
  __shared__ int sb[8];                 // {rlo,rhi,glo,ghi,clo,chi}
  const int t = threadIdx.x;
  if (t < 8) sb[t] = (t & 1) ? -1 : 4096;
  __syncthreads();

  const float sigma = 0.01f + expf(lns[0]);
  const float vsini = 0.9f + expf(lnv[0]);

  float rv = 0.f, gv = 0.f;
  if (t < TAPS) {
    float g = -4.5f + 0.01f * (float)t;
    float x = (299792.458f * g / 10500.0f) / vsini;
    float x2 = fminf(x * x, 1.0f);
    if (x2 < 1.0f) rv = 2.0f * sqrtf(1.0f - x2);  // 0.99999999f rounds to 1.0f
    gv = (1.0f / (sigma * sqrtf(2.0f * 3.1415926654f))) *
         expf(-0.5f * g * g / (sigma * sigma)) * 0.01f;
  }
  red[t] = rv;
  __syncthreads();
  for (int s = 512; s > 0; s >>= 1) {
    if (t < s) red[t] += red[t + s];
    __syncthreads();
  }
  const float rsum = red[0];

  const float rw = (t < TAPS) ? rv / rsum : 0.f;
  rk[t] = rw;
  gk[t] = gv;
  if (t < TAPS) {
    if (rw != 0.f)          { atomicMin(&sb[0], t); atomicMax(&sb[1], t); }
    if (fabsf(gv) > 1e-10f) { atomicMin(&sb[2], t); atomicMax(&sb[3], t); }
  }
  __syncthreads();
  const int rlo = sb[0], rhi = sb[1], glo = sb[2], ghi = sb[3];
  int flo = 450 - glo; if (flo < 0) flo = 0;
  int fhi = ghi - 450; if (fhi < 0) fhi = 0;

  if (blockIdx.x == 0) {
    // combined kernel comb[t2] = sum_j rot[j]*gauss[t2-j], t2 in [0,1800]
    for (int t2 = t; t2 < 2048; t2 += 1024) {
      float c = 0.f;
      if (t2 <= 1800) {
        int jmin = rlo > t2 - ghi ? rlo : t2 - ghi;
        int jmax = rhi < t2 - glo ? rhi : t2 - glo;
        for (int j = jmin; j <= jmax; ++j) c += rk[j] * gk[t2 - j];
      }
      ck[t2] = c;
      comb_w[t2] = c;
      if (t2 <= 1800 && fabsf(c) > 1e-12f) { atomicMin(&sb[4], t2); atomicMax(&sb[5], t2); }
    }
    __syncthreads();
    if (t == 0) {
      int clo = sb[4], chi = sb[5];
      if (chi < clo) { clo = 900; chi = 900; }
      // trim smallest-|w| end taps until aligned window width fits NK
      while (chi - (clo & ~3) + 1 > NK) {
        if (fabsf(ck[clo]) <= fabsf(ck[chi])) ++clo; else --chi;
      }
      bounds[0] = clo & ~3; bounds[1] = flo; bounds[2] = fhi;
    }
  } else if (blockIdx.x == 1) {
    // lo edge: pixels i in [0, flo); r[j] for j in [0, m)
    const int m = flo + fhi;
    float* rbuf = ck;
    for (int j = t; j < m; j += 1024) {
      float s = 0.f;
      int j0 = 450 - j > rlo ? 450 - j : rlo;  // f index >= 0
      for (int j2 = j0; j2 <= rhi; ++j2) s += rk[j2] * flux[j + j2 - 450];
      rbuf[j] = s;
    }
    __syncthreads();
    for (int i = t; i < flo; i += 1024) {
      float c = 0.f;
      int k0 = 450 - i > glo ? 450 - i : glo;  // r index >= 0
      for (int k = k0; k <= ghi; ++k) c += gk[k] * rbuf[i + k - 450];
      atomicAdd(&sums[ids[i]], c);
    }
  } else {
    // hi edge: pixels i in [n-fhi, n); r[j] for j in [n-m, n)
    const int m = flo + fhi;
    float* rbuf = ck;
    const int jbase = n - m;
    for (int jj = t; jj < m; jj += 1024) {
      int j = jbase + jj;
      float s = 0.f;
      int j2hi = n - 1 + 450 - j < rhi ? n - 1 + 450 - j : rhi;  // f index < n
      for (int j2 = rlo; j2 <= j2hi; ++j2) s += rk[j2] * flux[j + j2 - 450];
      rbuf[jj] = s;
    }
    __syncthreads();
    for (int ii = t; ii < fhi; ii += 1024) {
      int i = n - fhi + ii;
      float c = 0.f;
      int khi = n - 1 + 450 - i < ghi ? n - 1 + 450 - i : ghi;  // r index < n
      for (int k = glo; k <= khi; ++k) c += gk[k] * rbuf[i + k - 450 - jbase];
      atomicAdd(&sums[ids[i]], c);
    }
  }
}

// ---------------------------------------------------------------------------
// Kernel 2: fused combined-conv + segment-sum scatter + bin-boundary scan.
// - window: stride-11 b32 ring (odd dword stride -> conflict-free, m136)
// - weights: LDS 11+1-pad layout (3 aligned float4/group), software-
//   pipelined one group ahead in registers (kills per-group lgkm head stall)
// - block-uniform fast staging path for interior blocks
// - epilogue: run-merged atomic scatter into sums + bstart boundary writes
// ---------------------------------------------------------------------------
__global__ __launch_bounds__(CB) void conv_scatter(
    const float* __restrict__ flux, const float* __restrict__ comb_w,
    const int* __restrict__ bounds, const int* __restrict__ ids,
    float* __restrict__ sums, int* __restrict__ bstart, int n, int nbins) {
  __shared__ __align__(16) float lds[TILE];
  __shared__ __align__(16) float wl[NGRP * WPAD];
  const int tid = threadIdx.x;
  const int clo4 = __builtin_amdgcn_readfirstlane(bounds[0]);
  const int flo  = __builtin_amdgcn_readfirstlane(bounds[1]);
  const int fhi  = __builtin_amdgcn_readfirstlane(bounds[2]);
  const int blockBase = blockIdx.x * OPB;
  const int start = blockBase - 900 + clo4;  // multiple of 4 -> float4-aligned

  // stage window: lds[j] = f_zeropad[start + j]
  if (start >= 0 && start + STAGE_N <= n) {
    for (int j = tid * 4; j < STAGE_N; j += CB * 4)
      *reinterpret_cast<float4*>(&lds[j]) = ld4(flux + start + j);
  } else {
    for (int j = tid * 4; j < STAGE_N; j += CB * 4) {
      int g = start + j;
      float4 v;
      v.x = (unsigned)g       < (unsigned)n ? flux[g]     : 0.f;
      v.y = (unsigned)(g + 1) < (unsigned)n ? flux[g + 1] : 0.f;
      v.z = (unsigned)(g + 2) < (unsigned)n ? flux[g + 2] : 0.f;
      v.w = (unsigned)(g + 3) < (unsigned)n ? flux[g + 3] : 0.f;
      *reinterpret_cast<float4*>(&lds[j]) = v;
    }
  }
  // weights, padded: slot g*12+u <-> tap g*11+u (u<11); u>=11 -> 0 pad
  for (int k = tid; k < NGRP * WPAD; k += CB) {
    const int g = k / WPAD, u = k % WPAD;
    wl[k] = (u < R) ? comb_w[clo4 + g * R + u] : 0.f;
  }
  __syncthreads();

  const int idx0 = tid * R;
  float win[R];
#pragma unroll
  for (int r = 0; r < R; ++r) win[r] = lds[idx0 + r];
  float acc[R];
#pragma unroll
  for (int r = 0; r < R; ++r) acc[r] = 0.f;

  const float4* wl4 = reinterpret_cast<const float4*>(wl);
#define TAP(u, wv)                                                     \
  {                                                                    \
    _Pragma("unroll") for (int r = 0; r < R; ++r)                      \
        acc[r] = fmaf(wv, win[((u) + r) % R], acc[r]);                 \
    win[u] = lds[idx0 + kk + (u) + R];                                 \
  }
  float4 n0 = wl4[0], n1 = wl4[1], n2 = wl4[2];
#pragma unroll 2
  for (int g = 0; g < NGRP; ++g) {
    const int kk = g * R;
    const float4 q0 = n0, q1 = n1, q2 = n2;
    if (g + 1 < NGRP) {
      n0 = wl4[(g + 1) * 3 + 0];
      n1 = wl4[(g + 1) * 3 + 1];
      n2 = wl4[(g + 1) * 3 + 2];
    }
    TAP(0, q0.x)  TAP(1, q0.y)  TAP(2, q0.z)  TAP(3, q0.w)
    TAP(4, q1.x)  TAP(5, q1.y)  TAP(6, q1.z)  TAP(7, q1.w)
    TAP(8, q2.x)  TAP(9, q2.y)  TAP(10, q2.z)       // q2.w is pad
  }
#undef TAP

  // epilogue: run-merged scatter (skip edge pixels handled by prep) +
  // bin-start boundary writes for ALL owned pixels.
  const int base = blockBase + idx0;
  const int loskip = flo - base;        // r < loskip: edge-handled
  const int hicap = (n - fhi) - base;   // r >= hicap: edge-handled
  int prev = (base > 0) ? ((base < n) ? ids[base - 1] : 0) : -1;
  int cur = -1; float run = 0.f;
#pragma unroll
  for (int r = 0; r < R; ++r) {
    const int p = base + r;
    if (p < n) {
      const int id = ids[p];
      if (id != prev) {
        for (int b = prev + 1; b <= id; ++b) bstart[b] = p;
        prev = id;
      }
      if (r >= loskip && r < hicap) {
        if (id == cur) {
          run += acc[r];
        } else {
          if (cur >= 0) atomicAdd(&sums[cur], run);
          cur = id; run = acc[r];
        }
      }
    }
  }
  if (cur >= 0) atomicAdd(&sums[cur], run);
  // tail fill: thread owning pixel n-1 covers bins after the last id
  if (base < n && base + R > n - 1) {
    for (int b = prev + 1; b < nbins; ++b) bstart[b] = n;
  }
}

// ---------------------------------------------------------------------------
// Kernel 3: per-bin mean from precomputed bin starts (coalesced, no search).
// ---------------------------------------------------------------------------
__global__ __launch_bounds__(256) void seg_mean(
    const float* __restrict__ sums, const int* __restrict__ bstart,
    float* __restrict__ out, int out_n) {
  const int gid = blockIdx.x * blockDim.x + threadIdx.x;
  if (gid >= out_n) return;
  const int b = gid + 1;
  const int c = bstart[b + 1] - bstart[b];
  const float mean = sums[b] / (float)(c > 1 ? c : 1);
  out[gid] = fminf(fmaxf(mean, 0.f), 1.f);
}

// ---------------------------------------------------------------------------
extern "C" void kernel_launch(void* const* d_in, const int* in_sizes, int n_in,
                              void* d_out, int out_size, void* d_ws,
                              size_t ws_size, hipStream_t stream) {
  const float* flux = (const float*)d_in[0];
  const float* lns  = (const float*)d_in[1];
  const float* lnv  = (const float*)d_in[2];
  const int*   ids  = (const int*)d_in[3];
  float* out = (float*)d_out;
  const int n = in_sizes[0];
  const int nbins = out_size + 2;

  // ws layout (floats): comb_w[2048] | bounds(int)[64] | sums[nbins] |
  //                     bstart(int)[nbins+1]
  float* ws      = (float*)d_ws;
  float* comb_w  = ws;
  int*   bounds  = (int*)(ws + 2048);
  float* sums    = ws + 2112;
  int*   bstart  = (int*)(sums + nbins);

  hipMemsetAsync(sums, 0, (size_t)nbins * sizeof(float), stream);
  prep<<<3, 1024, 0, stream>>>(lns, lnv, flux, ids, comb_w, bounds, sums, n);
  const int nblk = (n + OPB - 1) / OPB;
  conv_scatter<<<nblk, CB, 0, stream>>>(flux, comb_w, bounds, ids, sums,
                                        bstart, n, nbins);
  seg_mean<<<(out_size + 255) / 256, 256, 0, stream>>>(sums, bstart, out,
                                                       out_size);
}